// Round 6
// baseline (1594.024 us; speedup 1.0000x reference)
//
#include <hip/hip_runtime.h>
#include <math.h>

#define BB 4
#define TT 4096
#define DD 768
#define SS 1024
#define S2 2048
#define KTOP 8
#define RWEIGHT 0.1f
#define TAU 6e-3f
#define AMB_CAP 1024

typedef __attribute__((ext_vector_type(8))) _Float16 f16x8;
typedef __attribute__((ext_vector_type(4))) float f32x4;
typedef _Float16 f16;

// ---------------------------------------------------------------------------
__global__ __launch_bounds__(256) void build_slots(
    const float* __restrict__ x, const float* __restrict__ pm,
    float* __restrict__ slots)
{
    int i = blockIdx.x * 256 + threadIdx.x;      // over S*D = 786432
    int s = i / DD;
    int d = i - s * DD;
    const float* xb = x + (size_t)(4 * s) * DD + d;
    slots[i] = 0.25f * (xb[0] + xb[DD] + xb[2 * DD] + xb[3 * DD]);
    slots[(size_t)SS * DD + i] = pm[i];
}

// ---------------------------------------------------------------------------
__global__ __launch_bounds__(256) void transpose768(
    const float* __restrict__ W, float* __restrict__ WT)
{
    __shared__ float t[32][33];
    int bx = blockIdx.x * 32, by = blockIdx.y * 32;
    int lx = threadIdx.x & 31, ly = threadIdx.x >> 5;   // 32 x 8
#pragma unroll
    for (int r = 0; r < 32; r += 8)
        t[ly + r][lx] = W[(size_t)(bx + ly + r) * 768 + by + lx];
    __syncthreads();
#pragma unroll
    for (int r = 0; r < 32; r += 8)
        WT[(size_t)(by + ly + r) * 768 + bx + lx] = t[lx][ly + r];
}

__global__ void zero1(int* p) { *p = 0; }

// ---------------------------------------------------------------------------
// 1-pass f16 MFMA NT GEMM: C[M,N] = alpha * A[M,768] @ B[N,768]^T + bscale*bias
// 128x128 tile, BK=32, 256 thr (4 waves 2x2), 16x16x32 f16 MFMA.
// Same (verified) staging/swizzle as the split kernel, h-term only.
// ---------------------------------------------------------------------------
__global__ __launch_bounds__(256) void mfma_nt_f16(
    const float* __restrict__ A, const float* __restrict__ B,
    const float* __restrict__ bias, float* __restrict__ C,
    int N, float alpha, float bscale)
{
    __shared__ f16 Ah[128 * 32], Bh[128 * 32];
    const int tid = threadIdx.x;
    const int lane = tid & 63;
    const int wc = (tid >> 6) & 1;
    const int wr = (tid >> 7) & 1;
    const size_t bm = (size_t)blockIdx.y * 128;
    const size_t bn = (size_t)blockIdx.x * 128;

    f32x4 acc[4][4];
#pragma unroll
    for (int i = 0; i < 4; ++i)
#pragma unroll
        for (int j = 0; j < 4; ++j) acc[i][j] = (f32x4){0.f, 0.f, 0.f, 0.f};

    const int srow = tid >> 1;
    const int skh = (tid & 1) * 16;
    const float* pa = A + (bm + srow) * 768 + skh;
    const float* pb = B + (bn + srow) * 768 + skh;
    const int c0 = skh >> 3;
    const int wo0 = srow * 32 + ((c0 ^ (srow & 3)) * 8);
    const int wo1 = srow * 32 + (((c0 + 1) ^ (srow & 3)) * 8);
    const int csw = (((lane >> 4) ^ (lane & 3)) * 8);

    for (int k0 = 0; k0 < 768; k0 += 32) {
        float4 a0 = *(const float4*)(pa + k0);
        float4 a1 = *(const float4*)(pa + k0 + 4);
        float4 a2 = *(const float4*)(pa + k0 + 8);
        float4 a3 = *(const float4*)(pa + k0 + 12);
        float4 b0 = *(const float4*)(pb + k0);
        float4 b1 = *(const float4*)(pb + k0 + 4);
        float4 b2 = *(const float4*)(pb + k0 + 8);
        float4 b3 = *(const float4*)(pb + k0 + 12);
        __syncthreads();
        {
            f16x8 h;
            h[0] = (f16)a0.x; h[1] = (f16)a0.y; h[2] = (f16)a0.z; h[3] = (f16)a0.w;
            h[4] = (f16)a1.x; h[5] = (f16)a1.y; h[6] = (f16)a1.z; h[7] = (f16)a1.w;
            *(f16x8*)&Ah[wo0] = h;
            h[0] = (f16)a2.x; h[1] = (f16)a2.y; h[2] = (f16)a2.z; h[3] = (f16)a2.w;
            h[4] = (f16)a3.x; h[5] = (f16)a3.y; h[6] = (f16)a3.z; h[7] = (f16)a3.w;
            *(f16x8*)&Ah[wo1] = h;
            h[0] = (f16)b0.x; h[1] = (f16)b0.y; h[2] = (f16)b0.z; h[3] = (f16)b0.w;
            h[4] = (f16)b1.x; h[5] = (f16)b1.y; h[6] = (f16)b1.z; h[7] = (f16)b1.w;
            *(f16x8*)&Bh[wo0] = h;
            h[0] = (f16)b2.x; h[1] = (f16)b2.y; h[2] = (f16)b2.z; h[3] = (f16)b2.w;
            h[4] = (f16)b3.x; h[5] = (f16)b3.y; h[6] = (f16)b3.z; h[7] = (f16)b3.w;
            *(f16x8*)&Bh[wo1] = h;
        }
        __syncthreads();

        f16x8 fah[4], fbh[4];
#pragma unroll
        for (int mi = 0; mi < 4; ++mi)
            fah[mi] = *(const f16x8*)&Ah[(wr * 64 + mi * 16 + (lane & 15)) * 32 + csw];
#pragma unroll
        for (int ni = 0; ni < 4; ++ni)
            fbh[ni] = *(const f16x8*)&Bh[(wc * 64 + ni * 16 + (lane & 15)) * 32 + csw];
#pragma unroll
        for (int mi = 0; mi < 4; ++mi)
#pragma unroll
            for (int ni = 0; ni < 4; ++ni)
                acc[mi][ni] = __builtin_amdgcn_mfma_f32_16x16x32_f16(
                    fah[mi], fbh[ni], acc[mi][ni], 0, 0, 0);
    }

    const int orow0 = wr * 64 + (lane >> 4) * 4;
    const int ocol0 = wc * 64 + (lane & 15);
#pragma unroll
    for (int mi = 0; mi < 4; ++mi)
#pragma unroll
        for (int ni = 0; ni < 4; ++ni) {
            size_t col = bn + ocol0 + ni * 16;
            float badd = bias ? bscale * bias[col] : 0.f;
            size_t rbase = bm + orow0 + mi * 16;
#pragma unroll
            for (int r = 0; r < 4; ++r)
                C[(rbase + r) * N + col] = alpha * acc[mi][ni][r] + badd;
        }
}

// ---------------------------------------------------------------------------
template <int NR>
__device__ void wave_topk(const float* __restrict__ srow, int lane,
                          float* topv, int* topi)
{
    float vals[32];
#pragma unroll
    for (int i = 0; i < 32; ++i) vals[i] = srow[lane + (i << 6)];
#pragma unroll
    for (int r = 0; r < NR; ++r) {
        float bvv = -3.4e38f; int bii = 0x7fffffff;
#pragma unroll
        for (int i = 0; i < 32; ++i)
            if (vals[i] > bvv) { bvv = vals[i]; bii = lane + (i << 6); }
#pragma unroll
        for (int off = 32; off > 0; off >>= 1) {
            float ov = __shfl_xor(bvv, off);
            int   oi = __shfl_xor(bii, off);
            if (ov > bvv || (ov == bvv && oi < bii)) { bvv = ov; bii = oi; }
        }
        topv[r] = bvv; topi[r] = bii;
        if ((bii & 63) == lane) vals[bii >> 6] = -3.4e38f;
    }
}

// ---------------------------------------------------------------------------
__global__ __launch_bounds__(256) void select_combine(
    const float* __restrict__ scores, const float* __restrict__ v,
    float* __restrict__ retrc,
    int* __restrict__ amb_count, int* __restrict__ amb_rows)
{
    const int lane = threadIdx.x & 63;
    const int wave = threadIdx.x >> 6;
    const int row = blockIdx.x * 4 + wave;

    float topv[9]; int topi[9];
    wave_topk<9>(scores + (size_t)row * S2, lane, topv, topi);

    if ((topv[7] - topv[8]) < TAU && lane == 0) {
        int idx = atomicAdd(amb_count, 1);
        if (idx < AMB_CAP) amb_rows[idx] = row;
    }

    float m = topv[0], w[KTOP], sum = 0.f;
#pragma unroll
    for (int r = 0; r < KTOP; ++r) { w[r] = expf(topv[r] - m); sum += w[r]; }
    float inv = 1.f / sum;

    const float4* v4 = (const float4*)v;
    float4* o4 = (float4*)(retrc + (size_t)row * DD);
#pragma unroll
    for (int c = 0; c < 3; ++c) {
        int col = c * 64 + lane;
        float4 accv = {0.f, 0.f, 0.f, 0.f};
#pragma unroll
        for (int r = 0; r < KTOP; ++r) {
            float4 vv = v4[(size_t)topi[r] * (DD / 4) + col];
            float wr = w[r] * inv;
            accv.x += wr * vv.x; accv.y += wr * vv.y;
            accv.z += wr * vv.z; accv.w += wr * vv.w;
        }
        o4[col] = accv;
    }
}

// ---------------------------------------------------------------------------
// F1: q64 for 4 amb rows per block. grid (3, AMB_CAP/4).
// Thread owns j; one Wq load feeds 4 row-FMAs (4x reuse).
// Block x==0: wave r extracts top-16 candidates for its row.
// ---------------------------------------------------------------------------
__global__ __launch_bounds__(256) void fixup_q(
    const int* __restrict__ amb_count, const int* __restrict__ amb_rows,
    const float* __restrict__ xc, const float* __restrict__ Wq,
    const float* __restrict__ bq, const float* __restrict__ scores,
    double* __restrict__ q64buf, int* __restrict__ cand)
{
    int n = *amb_count; if (n > AMB_CAP) n = AMB_CAP;
    const int i0 = blockIdx.y * 4;
    if (i0 >= n) return;
    const int nr = (n - i0 < 4) ? (n - i0) : 4;
    const int tid = threadIdx.x;
    const int j = blockIdx.x * 256 + tid;

    __shared__ float xs[4][768];
    for (int r = 0; r < nr; ++r) {
        const float* src = xc + (size_t)amb_rows[i0 + r] * 768;
        for (int t = tid; t < 768; t += 256) xs[r][t] = src[t];
    }
    __syncthreads();

    if (blockIdx.x == 0) {
        const int wave = tid >> 6, lane = tid & 63;
        if (wave < nr) {
            float tv[16]; int ti[16];
            wave_topk<16>(scores + (size_t)amb_rows[i0 + wave] * S2, lane, tv, ti);
            if (lane < 16) cand[(i0 + wave) * 16 + lane] = ti[lane];
        }
    }

    double a0 = 0.0, a1 = 0.0, a2 = 0.0, a3 = 0.0;
    const float* wp = Wq + j;
#pragma unroll 4
    for (int k = 0; k < 768; ++k) {
        double w = (double)wp[(size_t)k * 768];
        a0 = fma((double)xs[0][k], w, a0);
        a1 = fma((double)xs[1][k], w, a1);
        a2 = fma((double)xs[2][k], w, a2);
        a3 = fma((double)xs[3][k], w, a3);
    }
    double acc[4] = {a0, a1, a2, a3};
    for (int r = 0; r < nr; ++r)
        q64buf[(size_t)(i0 + r) * 768 + j] = acc[r] + (double)bq[j];
}

// ---------------------------------------------------------------------------
// F2: u = Wk @ q64 for 4 amb rows per block. grid (3, AMB_CAP/4).
// Block x==0: wave r computes bk.q64 for its row.
// ---------------------------------------------------------------------------
__global__ __launch_bounds__(256) void fixup_u(
    const int* __restrict__ amb_count,
    const float* __restrict__ WkT, const float* __restrict__ bk,
    const double* __restrict__ q64buf,
    double* __restrict__ ubuf, double* __restrict__ bkqbuf)
{
    int n = *amb_count; if (n > AMB_CAP) n = AMB_CAP;
    const int i0 = blockIdx.y * 4;
    if (i0 >= n) return;
    const int nr = (n - i0 < 4) ? (n - i0) : 4;
    const int tid = threadIdx.x;
    const int t = blockIdx.x * 256 + tid;

    __shared__ double qs[4][768];
    for (int r = 0; r < nr; ++r) {
        const double* src = q64buf + (size_t)(i0 + r) * 768;
        for (int k = tid; k < 768; k += 256) qs[r][k] = src[k];
    }
    __syncthreads();

    if (blockIdx.x == 0) {
        const int wave = tid >> 6, lane = tid & 63;
        if (wave < nr) {
            double p = 0.0;
#pragma unroll
            for (int c = 0; c < 12; ++c) {
                int jj = lane + (c << 6);
                p = fma((double)bk[jj], qs[wave][jj], p);
            }
#pragma unroll
            for (int off = 32; off; off >>= 1) p += __shfl_xor(p, off);
            if (lane == 0) bkqbuf[i0 + wave] = p;
        }
    }

    double a0 = 0.0, a1 = 0.0, a2 = 0.0, a3 = 0.0;
    const float* wp = WkT + t;
#pragma unroll 4
    for (int jj = 0; jj < 768; ++jj) {
        double w = (double)wp[(size_t)jj * 768];
        a0 = fma(qs[0][jj], w, a0);
        a1 = fma(qs[1][jj], w, a1);
        a2 = fma(qs[2][jj], w, a2);
        a3 = fma(qs[3][jj], w, a3);
    }
    double acc[4] = {a0, a1, a2, a3};
    for (int r = 0; r < nr; ++r)
        ubuf[(size_t)(i0 + r) * 768 + t] = acc[r];
}

// ---------------------------------------------------------------------------
// F3: per amb row: 16 exact scores via slot.u + bkq, f64 top-8, f64 softmax,
// combine, overwrite retr row. grid (AMB_CAP).
// ---------------------------------------------------------------------------
__global__ __launch_bounds__(256) void fixup_sel(
    const int* __restrict__ amb_count, const int* __restrict__ amb_rows,
    const float* __restrict__ xb, const float* __restrict__ pm,
    const int* __restrict__ cand, const double* __restrict__ ubuf,
    const double* __restrict__ bkqbuf, const float* __restrict__ v,
    float* __restrict__ retrc)
{
    int n = *amb_count; if (n > AMB_CAP) n = AMB_CAP;
    const int i = blockIdx.x;
    if (i >= n) return;
    const int tid = threadIdx.x;
    const int lane = tid & 63;
    const int wave = tid >> 6;
    const int row = amb_rows[i];

    __shared__ double us[768];
    __shared__ double cs_s[16];
    __shared__ float wsm[KTOP];
    __shared__ int seli[KTOP];

    const double* urow = ubuf + (size_t)i * 768;
    for (int t = tid; t < 768; t += 256) us[t] = urow[t];
    __syncthreads();

    const double ISQ = 1.0 / sqrt((double)DD);
    const double bkq = bkqbuf[i];
#pragma unroll
    for (int c = wave; c < 16; c += 4) {
        int s = cand[i * 16 + c];
        double p = 0.0;
        if (s < SS) {
            const float* xr = xb + (size_t)(4 * s) * 768;
#pragma unroll
            for (int t = 0; t < 12; ++t) {
                int j2 = lane + (t << 6);
                double sv = 0.25 * ((double)xr[j2] + (double)xr[j2 + 768] +
                                    (double)xr[j2 + 1536] + (double)xr[j2 + 2304]);
                p = fma(sv, us[j2], p);
            }
        } else {
            const float* pr = pm + (size_t)(s - SS) * 768;
#pragma unroll
            for (int t = 0; t < 12; ++t) {
                int j2 = lane + (t << 6);
                p = fma((double)pr[j2], us[j2], p);
            }
        }
#pragma unroll
        for (int off = 32; off; off >>= 1) p += __shfl_xor(p, off);
        if (lane == 0) cs_s[c] = (p + bkq) * ISQ;
    }
    __syncthreads();

    if (tid == 0) {
        double cs[16]; int ci[16];
        for (int c = 0; c < 16; ++c) { cs[c] = cs_s[c]; ci[c] = cand[i * 16 + c]; }
        unsigned used = 0;
        double sv[KTOP]; int sx[KTOP];
        for (int r = 0; r < KTOP; ++r) {
            int bi = -1;
            for (int c = 0; c < 16; ++c) {
                if (used & (1u << c)) continue;
                if (bi < 0 || cs[c] > cs[bi] ||
                    (cs[c] == cs[bi] && ci[c] < ci[bi])) bi = c;
            }
            used |= (1u << bi); sv[r] = cs[bi]; sx[r] = ci[bi];
        }
        double mx = sv[0], es[KTOP], ssum = 0.0;
        for (int r = 0; r < KTOP; ++r) { es[r] = exp(sv[r] - mx); ssum += es[r]; }
        for (int r = 0; r < KTOP; ++r) { wsm[r] = (float)(es[r] / ssum); seli[r] = sx[r]; }
    }
    __syncthreads();
    for (int j = tid; j < 768; j += 256) {
        float o = 0.f;
#pragma unroll
        for (int r = 0; r < KTOP; ++r) o += wsm[r] * v[(size_t)seli[r] * 768 + j];
        retrc[(size_t)row * 768 + j] = o;
    }
}

// ---------------------------------------------------------------------------
extern "C" void kernel_launch(void* const* d_in, const int* in_sizes, int n_in,
                              void* d_out, int out_size, void* d_ws, size_t ws_size,
                              hipStream_t stream)
{
    const float* x  = (const float*)d_in[0];
    const float* Wq = (const float*)d_in[1];
    const float* bq = (const float*)d_in[2];
    const float* Wk = (const float*)d_in[3];
    const float* bk = (const float*)d_in[4];
    const float* Wv = (const float*)d_in[5];
    const float* bv = (const float*)d_in[6];
    const float* Wp = (const float*)d_in[7];
    const float* bp = (const float*)d_in[8];
    const float* pm = (const float*)d_in[9];
    float* out = (float*)d_out;
    float* ws  = (float*)d_ws;

    const float inv_sqrt_d = (float)(1.0 / sqrt((double)DD));
    const size_t TD  = (size_t)TT * DD;
    const size_t SD2 = (size_t)S2 * DD;
    const size_t WSZ = (size_t)DD * DD;

    float* p = ws;
    float* WqT = p; p += WSZ;
    float* WkT = p; p += WSZ;
    float* WvT = p; p += WSZ;
    float* WpT = p; p += WSZ;
    float* slots = p; p += SD2;
    float* q32 = p; p += TD;
    float* k32 = p; p += SD2;
    float* v32 = p; p += SD2;
    float* retr = p; p += TD;
    double* q64buf = (double*)p; p += (size_t)AMB_CAP * DD * 2;
    double* ubuf   = (double*)p; p += (size_t)AMB_CAP * DD * 2;
    double* bkqbuf = (double*)p; p += AMB_CAP * 2;
    int* cand = (int*)p; p += (size_t)AMB_CAP * 16;
    int* ambc = (int*)p; p += 64;
    int* ambrows = (int*)p; p += AMB_CAP;
    float* scores = p;
    size_t used = (size_t)(p - ws);

    long tc = TT;
    while (tc > 512 && (used + (size_t)tc * S2) * 4 > ws_size) tc >>= 1;

    transpose768<<<dim3(24, 24), 256, 0, stream>>>(Wq, WqT);
    transpose768<<<dim3(24, 24), 256, 0, stream>>>(Wk, WkT);
    transpose768<<<dim3(24, 24), 256, 0, stream>>>(Wv, WvT);
    transpose768<<<dim3(24, 24), 256, 0, stream>>>(Wp, WpT);

    for (int b = 0; b < BB; ++b) {
        const float* xb = x + (size_t)b * TD;
        build_slots<<<(SS * DD) / 256, 256, 0, stream>>>(xb, pm, slots);
        mfma_nt_f16<<<dim3(6, 32), 256, 0, stream>>>(
            xb, WqT, bq, q32, DD, 1.f, 1.f);
        mfma_nt_f16<<<dim3(6, 16), 256, 0, stream>>>(
            slots, WkT, bk, k32, DD, 1.f, 1.f);
        mfma_nt_f16<<<dim3(6, 16), 256, 0, stream>>>(
            slots, WvT, bv, v32, DD, 1.f, 1.f);

        for (long t0 = 0; t0 < TT; t0 += tc) {
            zero1<<<1, 1, 0, stream>>>(ambc);
            mfma_nt_f16<<<dim3(16, tc / 128), 256, 0, stream>>>(
                q32 + (size_t)t0 * DD, k32, (const float*)nullptr, scores,
                S2, inv_sqrt_d, 0.f);
            select_combine<<<tc / 4, 256, 0, stream>>>(
                scores, v32, retr + (size_t)t0 * DD, ambc, ambrows);
            fixup_q<<<dim3(3, AMB_CAP / 4), 256, 0, stream>>>(
                ambc, ambrows, xb + (size_t)t0 * DD, Wq, bq, scores,
                q64buf, cand);
            fixup_u<<<dim3(3, AMB_CAP / 4), 256, 0, stream>>>(
                ambc, WkT, bk, q64buf, ubuf, bkqbuf);
            fixup_sel<<<AMB_CAP, 256, 0, stream>>>(
                ambc, ambrows, xb, pm, cand, ubuf, bkqbuf, v32,
                retr + (size_t)t0 * DD);
        }

        mfma_nt_f16<<<dim3(6, 32), 256, 0, stream>>>(
            retr, WpT, bp, out + (size_t)b * TD, DD, RWEIGHT, RWEIGHT);
    }
}

// Round 7
// 1102.070 us; speedup vs baseline: 1.4464x; 1.4464x over previous
//
#include <hip/hip_runtime.h>
#include <math.h>

#define BB 4
#define TT 4096
#define DD 768
#define SS 1024
#define S2 2048
#define KTOP 8
#define RWEIGHT 0.1f
#define TAU 2e-4f
#define AMB_CAP 256

typedef __attribute__((ext_vector_type(8))) _Float16 f16x8;
typedef __attribute__((ext_vector_type(4))) float f32x4;
typedef _Float16 f16;

// ---------------------------------------------------------------------------
__global__ __launch_bounds__(256) void build_slots(
    const float* __restrict__ x, const float* __restrict__ pm,
    float* __restrict__ slots)
{
    int i = blockIdx.x * 256 + threadIdx.x;      // over S*D = 786432
    int s = i / DD;
    int d = i - s * DD;
    const float* xb = x + (size_t)(4 * s) * DD + d;
    slots[i] = 0.25f * (xb[0] + xb[DD] + xb[2 * DD] + xb[3 * DD]);
    slots[(size_t)SS * DD + i] = pm[i];
}

// ---------------------------------------------------------------------------
__global__ __launch_bounds__(256) void transpose768(
    const float* __restrict__ W, float* __restrict__ WT)
{
    __shared__ float t[32][33];
    int bx = blockIdx.x * 32, by = blockIdx.y * 32;
    int lx = threadIdx.x & 31, ly = threadIdx.x >> 5;   // 32 x 8
#pragma unroll
    for (int r = 0; r < 32; r += 8)
        t[ly + r][lx] = W[(size_t)(bx + ly + r) * 768 + by + lx];
    __syncthreads();
#pragma unroll
    for (int r = 0; r < 32; r += 8)
        WT[(size_t)(by + ly + r) * 768 + bx + lx] = t[lx][ly + r];
}

__global__ void zero1(int* p) { *p = 0; }

// ---------------------------------------------------------------------------
// 3-pass f16-split MFMA NT GEMM (selection-critical path: q, k, scores).
// C = alpha * A[M,768] @ B[N,768]^T + bscale*bias; a = h + m, hh+hm+mh.
// ---------------------------------------------------------------------------
__global__ __launch_bounds__(256) void mfma_nt_split(
    const float* __restrict__ A, const float* __restrict__ B,
    const float* __restrict__ bias, float* __restrict__ C,
    int N, float alpha, float bscale)
{
    __shared__ f16 Ah[128 * 32], Am[128 * 32], Bh[128 * 32], Bm[128 * 32];
    const int tid = threadIdx.x;
    const int lane = tid & 63;
    const int wc = (tid >> 6) & 1;
    const int wr = (tid >> 7) & 1;
    const size_t bm = (size_t)blockIdx.y * 128;
    const size_t bn = (size_t)blockIdx.x * 128;

    f32x4 acc[4][4];
#pragma unroll
    for (int i = 0; i < 4; ++i)
#pragma unroll
        for (int j = 0; j < 4; ++j) acc[i][j] = (f32x4){0.f, 0.f, 0.f, 0.f};

    const int srow = tid >> 1;
    const int skh = (tid & 1) * 16;
    const float* pa = A + (bm + srow) * 768 + skh;
    const float* pb = B + (bn + srow) * 768 + skh;
    const int c0 = skh >> 3;
    const int wo0 = srow * 32 + ((c0 ^ (srow & 3)) * 8);
    const int wo1 = srow * 32 + (((c0 + 1) ^ (srow & 3)) * 8);
    const int csw = (((lane >> 4) ^ (lane & 3)) * 8);

    for (int k0 = 0; k0 < 768; k0 += 32) {
        float4 a0 = *(const float4*)(pa + k0);
        float4 a1 = *(const float4*)(pa + k0 + 4);
        float4 a2 = *(const float4*)(pa + k0 + 8);
        float4 a3 = *(const float4*)(pa + k0 + 12);
        float4 b0 = *(const float4*)(pb + k0);
        float4 b1 = *(const float4*)(pb + k0 + 4);
        float4 b2 = *(const float4*)(pb + k0 + 8);
        float4 b3 = *(const float4*)(pb + k0 + 12);
        __syncthreads();
        {
            float av[16] = {a0.x, a0.y, a0.z, a0.w, a1.x, a1.y, a1.z, a1.w,
                            a2.x, a2.y, a2.z, a2.w, a3.x, a3.y, a3.z, a3.w};
            float bv[16] = {b0.x, b0.y, b0.z, b0.w, b1.x, b1.y, b1.z, b1.w,
                            b2.x, b2.y, b2.z, b2.w, b3.x, b3.y, b3.z, b3.w};
            f16x8 h, m;
#pragma unroll
            for (int j = 0; j < 8; ++j) {
                f16 hh = (f16)av[j]; h[j] = hh; m[j] = (f16)(av[j] - (float)hh);
            }
            *(f16x8*)&Ah[wo0] = h; *(f16x8*)&Am[wo0] = m;
#pragma unroll
            for (int j = 0; j < 8; ++j) {
                f16 hh = (f16)av[j + 8]; h[j] = hh; m[j] = (f16)(av[j + 8] - (float)hh);
            }
            *(f16x8*)&Ah[wo1] = h; *(f16x8*)&Am[wo1] = m;
#pragma unroll
            for (int j = 0; j < 8; ++j) {
                f16 hh = (f16)bv[j]; h[j] = hh; m[j] = (f16)(bv[j] - (float)hh);
            }
            *(f16x8*)&Bh[wo0] = h; *(f16x8*)&Bm[wo0] = m;
#pragma unroll
            for (int j = 0; j < 8; ++j) {
                f16 hh = (f16)bv[j + 8]; h[j] = hh; m[j] = (f16)(bv[j + 8] - (float)hh);
            }
            *(f16x8*)&Bh[wo1] = h; *(f16x8*)&Bm[wo1] = m;
        }
        __syncthreads();

        f16x8 fah[4], fam[4], fbh[4], fbm[4];
#pragma unroll
        for (int mi = 0; mi < 4; ++mi) {
            int off = (wr * 64 + mi * 16 + (lane & 15)) * 32 + csw;
            fah[mi] = *(const f16x8*)&Ah[off];
            fam[mi] = *(const f16x8*)&Am[off];
        }
#pragma unroll
        for (int ni = 0; ni < 4; ++ni) {
            int off = (wc * 64 + ni * 16 + (lane & 15)) * 32 + csw;
            fbh[ni] = *(const f16x8*)&Bh[off];
            fbm[ni] = *(const f16x8*)&Bm[off];
        }
#pragma unroll
        for (int mi = 0; mi < 4; ++mi)
#pragma unroll
            for (int ni = 0; ni < 4; ++ni) {
                acc[mi][ni] = __builtin_amdgcn_mfma_f32_16x16x32_f16(
                    fah[mi], fbh[ni], acc[mi][ni], 0, 0, 0);
                acc[mi][ni] = __builtin_amdgcn_mfma_f32_16x16x32_f16(
                    fah[mi], fbm[ni], acc[mi][ni], 0, 0, 0);
                acc[mi][ni] = __builtin_amdgcn_mfma_f32_16x16x32_f16(
                    fam[mi], fbh[ni], acc[mi][ni], 0, 0, 0);
            }
    }

    const int orow0 = wr * 64 + (lane >> 4) * 4;
    const int ocol0 = wc * 64 + (lane & 15);
#pragma unroll
    for (int mi = 0; mi < 4; ++mi)
#pragma unroll
        for (int ni = 0; ni < 4; ++ni) {
            size_t col = bn + ocol0 + ni * 16;
            float badd = bias ? bscale * bias[col] : 0.f;
            size_t rbase = bm + orow0 + mi * 16;
#pragma unroll
            for (int r = 0; r < 4; ++r)
                C[(rbase + r) * N + col] = alpha * acc[mi][ni][r] + badd;
        }
}

// ---------------------------------------------------------------------------
// 1-pass f16 MFMA NT GEMM (value path: v, proj).
// ---------------------------------------------------------------------------
__global__ __launch_bounds__(256) void mfma_nt_f16(
    const float* __restrict__ A, const float* __restrict__ B,
    const float* __restrict__ bias, float* __restrict__ C,
    int N, float alpha, float bscale)
{
    __shared__ f16 Ah[128 * 32], Bh[128 * 32];
    const int tid = threadIdx.x;
    const int lane = tid & 63;
    const int wc = (tid >> 6) & 1;
    const int wr = (tid >> 7) & 1;
    const size_t bm = (size_t)blockIdx.y * 128;
    const size_t bn = (size_t)blockIdx.x * 128;

    f32x4 acc[4][4];
#pragma unroll
    for (int i = 0; i < 4; ++i)
#pragma unroll
        for (int j = 0; j < 4; ++j) acc[i][j] = (f32x4){0.f, 0.f, 0.f, 0.f};

    const int srow = tid >> 1;
    const int skh = (tid & 1) * 16;
    const float* pa = A + (bm + srow) * 768 + skh;
    const float* pb = B + (bn + srow) * 768 + skh;
    const int c0 = skh >> 3;
    const int wo0 = srow * 32 + ((c0 ^ (srow & 3)) * 8);
    const int wo1 = srow * 32 + (((c0 + 1) ^ (srow & 3)) * 8);
    const int csw = (((lane >> 4) ^ (lane & 3)) * 8);

    for (int k0 = 0; k0 < 768; k0 += 32) {
        float4 a0 = *(const float4*)(pa + k0);
        float4 a1 = *(const float4*)(pa + k0 + 4);
        float4 a2 = *(const float4*)(pa + k0 + 8);
        float4 a3 = *(const float4*)(pa + k0 + 12);
        float4 b0 = *(const float4*)(pb + k0);
        float4 b1 = *(const float4*)(pb + k0 + 4);
        float4 b2 = *(const float4*)(pb + k0 + 8);
        float4 b3 = *(const float4*)(pb + k0 + 12);
        __syncthreads();
        {
            f16x8 h;
            h[0] = (f16)a0.x; h[1] = (f16)a0.y; h[2] = (f16)a0.z; h[3] = (f16)a0.w;
            h[4] = (f16)a1.x; h[5] = (f16)a1.y; h[6] = (f16)a1.z; h[7] = (f16)a1.w;
            *(f16x8*)&Ah[wo0] = h;
            h[0] = (f16)a2.x; h[1] = (f16)a2.y; h[2] = (f16)a2.z; h[3] = (f16)a2.w;
            h[4] = (f16)a3.x; h[5] = (f16)a3.y; h[6] = (f16)a3.z; h[7] = (f16)a3.w;
            *(f16x8*)&Ah[wo1] = h;
            h[0] = (f16)b0.x; h[1] = (f16)b0.y; h[2] = (f16)b0.z; h[3] = (f16)b0.w;
            h[4] = (f16)b1.x; h[5] = (f16)b1.y; h[6] = (f16)b1.z; h[7] = (f16)b1.w;
            *(f16x8*)&Bh[wo0] = h;
            h[0] = (f16)b2.x; h[1] = (f16)b2.y; h[2] = (f16)b2.z; h[3] = (f16)b2.w;
            h[4] = (f16)b3.x; h[5] = (f16)b3.y; h[6] = (f16)b3.z; h[7] = (f16)b3.w;
            *(f16x8*)&Bh[wo1] = h;
        }
        __syncthreads();

        f16x8 fah[4], fbh[4];
#pragma unroll
        for (int mi = 0; mi < 4; ++mi)
            fah[mi] = *(const f16x8*)&Ah[(wr * 64 + mi * 16 + (lane & 15)) * 32 + csw];
#pragma unroll
        for (int ni = 0; ni < 4; ++ni)
            fbh[ni] = *(const f16x8*)&Bh[(wc * 64 + ni * 16 + (lane & 15)) * 32 + csw];
#pragma unroll
        for (int mi = 0; mi < 4; ++mi)
#pragma unroll
            for (int ni = 0; ni < 4; ++ni)
                acc[mi][ni] = __builtin_amdgcn_mfma_f32_16x16x32_f16(
                    fah[mi], fbh[ni], acc[mi][ni], 0, 0, 0);
    }

    const int orow0 = wr * 64 + (lane >> 4) * 4;
    const int ocol0 = wc * 64 + (lane & 15);
#pragma unroll
    for (int mi = 0; mi < 4; ++mi)
#pragma unroll
        for (int ni = 0; ni < 4; ++ni) {
            size_t col = bn + ocol0 + ni * 16;
            float badd = bias ? bscale * bias[col] : 0.f;
            size_t rbase = bm + orow0 + mi * 16;
#pragma unroll
            for (int r = 0; r < 4; ++r)
                C[(rbase + r) * N + col] = alpha * acc[mi][ni][r] + badd;
        }
}

// ---------------------------------------------------------------------------
// select_combine: one wave per row. top-9 (extended to 16 iff ambiguous);
// gap test appends row + its top-16 candidates; softmax top-8; combine.
// ---------------------------------------------------------------------------
__global__ __launch_bounds__(256) void select_combine(
    const float* __restrict__ scores, const float* __restrict__ v,
    float* __restrict__ retrc,
    int* __restrict__ amb_count, int* __restrict__ amb_rows,
    int* __restrict__ cand)
{
    const int lane = threadIdx.x & 63;
    const int wave = threadIdx.x >> 6;
    const int row = blockIdx.x * 4 + wave;

    const float* srow = scores + (size_t)row * S2;
    float vals[32];
#pragma unroll
    for (int i = 0; i < 32; ++i) vals[i] = srow[lane + (i << 6)];

    float topv[16]; int topi[16];
    bool amb = false;
    int nr = 9;
    for (int r = 0; r < 16; ++r) {
        if (r >= nr) break;
        float bvv = -3.4e38f; int bii = 0x7fffffff;
#pragma unroll
        for (int i = 0; i < 32; ++i)
            if (vals[i] > bvv) { bvv = vals[i]; bii = lane + (i << 6); }
#pragma unroll
        for (int off = 32; off > 0; off >>= 1) {
            float ov = __shfl_xor(bvv, off);
            int   oi = __shfl_xor(bii, off);
            if (ov > bvv || (ov == bvv && oi < bii)) { bvv = ov; bii = oi; }
        }
        topv[r] = bvv; topi[r] = bii;
        if ((bii & 63) == lane) vals[bii >> 6] = -3.4e38f;
        if (r == 8) {
            amb = (topv[7] - topv[8]) < TAU;   // wave-uniform
            if (amb) nr = 16;
        }
    }

    if (amb) {
        int idx = 0;
        if (lane == 0) idx = atomicAdd(amb_count, 1);
        idx = __shfl(idx, 0);
        if (idx < AMB_CAP) {
            if (lane == 0) amb_rows[idx] = row;
            if (lane < 16) cand[idx * 16 + lane] = topi[lane];
        }
    }

    float m = topv[0], w[KTOP], sum = 0.f;
#pragma unroll
    for (int r = 0; r < KTOP; ++r) { w[r] = expf(topv[r] - m); sum += w[r]; }
    float inv = 1.f / sum;

    const float4* v4 = (const float4*)v;
    float4* o4 = (float4*)(retrc + (size_t)row * DD);
#pragma unroll
    for (int c = 0; c < 3; ++c) {
        int col = c * 64 + lane;
        float4 accv = {0.f, 0.f, 0.f, 0.f};
#pragma unroll
        for (int r = 0; r < KTOP; ++r) {
            float4 vv = v4[(size_t)topi[r] * (DD / 4) + col];
            float wr = w[r] * inv;
            accv.x += wr * vv.x; accv.y += wr * vv.y;
            accv.z += wr * vv.z; accv.w += wr * vv.w;
        }
        o4[col] = accv;
    }
}

// ---------------------------------------------------------------------------
// F1: q64[i][j] = f64(x_row . Wq[:,j]) + bq[j].  grid (12, AMB_CAP).
// Block = 64 j-cols x 4 k-segments of 192 (serial depth 192, not 768).
// ---------------------------------------------------------------------------
__global__ __launch_bounds__(256) void fixup_q(
    const int* __restrict__ amb_count, const int* __restrict__ amb_rows,
    const float* __restrict__ xc, const float* __restrict__ Wq,
    const float* __restrict__ bq, double* __restrict__ q64buf)
{
    int n = *amb_count; if (n > AMB_CAP) n = AMB_CAP;
    const int i = blockIdx.y;
    if (i >= n) return;
    const int tid = threadIdx.x;
    const int jl = tid & 63;
    const int ks = tid >> 6;
    const int j = blockIdx.x * 64 + jl;
    const int row = amb_rows[i];

    __shared__ float xs[768];
    __shared__ double ps[4][64];
    for (int t = tid; t < 768; t += 256) xs[t] = xc[(size_t)row * 768 + t];
    __syncthreads();

    double a0 = 0.0, a1 = 0.0;
    const float* wp = Wq + j;
    const int k0 = ks * 192;
#pragma unroll 8
    for (int k = 0; k < 192; k += 2) {
        a0 = fma((double)xs[k0 + k],     (double)wp[(size_t)(k0 + k) * 768],     a0);
        a1 = fma((double)xs[k0 + k + 1], (double)wp[(size_t)(k0 + k + 1) * 768], a1);
    }
    ps[ks][jl] = a0 + a1;
    __syncthreads();
    if (ks == 0)
        q64buf[(size_t)i * 768 + j] =
            ((ps[0][jl] + ps[1][jl]) + (ps[2][jl] + ps[3][jl])) + (double)bq[j];
}

// ---------------------------------------------------------------------------
// F2: u[i][t] = sum_j WkT[j][t] * q64[i][j].  grid (12, AMB_CAP).
// Block = 64 t-cols x 4 j-segments. Block x==0 also computes bk.q64.
// ---------------------------------------------------------------------------
__global__ __launch_bounds__(256) void fixup_u(
    const int* __restrict__ amb_count,
    const float* __restrict__ WkT, const float* __restrict__ bk,
    const double* __restrict__ q64buf,
    double* __restrict__ ubuf, double* __restrict__ bkqbuf)
{
    int n = *amb_count; if (n > AMB_CAP) n = AMB_CAP;
    const int i = blockIdx.y;
    if (i >= n) return;
    const int tid = threadIdx.x;
    const int tl = tid & 63;
    const int js = tid >> 6;
    const int t = blockIdx.x * 64 + tl;

    __shared__ double qs[768];
    __shared__ double ps[4][64];
    const double* qrow = q64buf + (size_t)i * 768;
    for (int k = tid; k < 768; k += 256) qs[k] = qrow[k];
    __syncthreads();

    double a0 = 0.0, a1 = 0.0;
    const float* wp = WkT + t;
    const int j0 = js * 192;
#pragma unroll 8
    for (int k = 0; k < 192; k += 2) {
        a0 = fma((double)wp[(size_t)(j0 + k) * 768],     qs[j0 + k],     a0);
        a1 = fma((double)wp[(size_t)(j0 + k + 1) * 768], qs[j0 + k + 1], a1);
    }
    ps[js][tl] = a0 + a1;
    __syncthreads();
    if (js == 0)
        ubuf[(size_t)i * 768 + t] = (ps[0][tl] + ps[1][tl]) + (ps[2][tl] + ps[3][tl]);

    if (blockIdx.x == 0 && tid < 64) {
        double p = 0.0;
#pragma unroll
        for (int c = 0; c < 12; ++c) {
            int jj = tid + (c << 6);
            p = fma((double)bk[jj], qs[jj], p);
        }
#pragma unroll
        for (int off = 32; off; off >>= 1) p += __shfl_xor(p, off);
        if (tid == 0) bkqbuf[i] = p;
    }
}

// ---------------------------------------------------------------------------
// F3: per amb row: 16 exact scores via slot.u + bkq, f64 top-8 (val desc,
// idx asc), f64 softmax, combine, overwrite retr row. grid (AMB_CAP).
// ---------------------------------------------------------------------------
__global__ __launch_bounds__(256) void fixup_sel(
    const int* __restrict__ amb_count, const int* __restrict__ amb_rows,
    const float* __restrict__ xb, const float* __restrict__ pm,
    const int* __restrict__ cand, const double* __restrict__ ubuf,
    const double* __restrict__ bkqbuf, const float* __restrict__ v,
    float* __restrict__ retrc)
{
    int n = *amb_count; if (n > AMB_CAP) n = AMB_CAP;
    const int i = blockIdx.x;
    if (i >= n) return;
    const int tid = threadIdx.x;
    const int lane = tid & 63;
    const int wave = tid >> 6;
    const int row = amb_rows[i];

    __shared__ double us[768];
    __shared__ double cs_s[16];
    __shared__ float wsm[KTOP];
    __shared__ int seli[KTOP];

    const double* urow = ubuf + (size_t)i * 768;
    for (int t = tid; t < 768; t += 256) us[t] = urow[t];
    __syncthreads();

    const double ISQ = 1.0 / sqrt((double)DD);
    const double bkq = bkqbuf[i];
#pragma unroll
    for (int c = wave; c < 16; c += 4) {
        int s = cand[i * 16 + c];
        double p = 0.0;
        if (s < SS) {
            const float* xr = xb + (size_t)(4 * s) * 768;
#pragma unroll
            for (int t = 0; t < 12; ++t) {
                int j2 = lane + (t << 6);
                double sv = 0.25 * ((double)xr[j2] + (double)xr[j2 + 768] +
                                    (double)xr[j2 + 1536] + (double)xr[j2 + 2304]);
                p = fma(sv, us[j2], p);
            }
        } else {
            const float* pr = pm + (size_t)(s - SS) * 768;
#pragma unroll
            for (int t = 0; t < 12; ++t) {
                int j2 = lane + (t << 6);
                p = fma((double)pr[j2], us[j2], p);
            }
        }
#pragma unroll
        for (int off = 32; off; off >>= 1) p += __shfl_xor(p, off);
        if (lane == 0) cs_s[c] = (p + bkq) * ISQ;
    }
    __syncthreads();

    if (tid == 0) {
        double cs[16]; int ci[16];
        for (int c = 0; c < 16; ++c) { cs[c] = cs_s[c]; ci[c] = cand[i * 16 + c]; }
        unsigned used = 0;
        double sv[KTOP]; int sx[KTOP];
        for (int r = 0; r < KTOP; ++r) {
            int bi = -1;
            for (int c = 0; c < 16; ++c) {
                if (used & (1u << c)) continue;
                if (bi < 0 || cs[c] > cs[bi] ||
                    (cs[c] == cs[bi] && ci[c] < ci[bi])) bi = c;
            }
            used |= (1u << bi); sv[r] = cs[bi]; sx[r] = ci[bi];
        }
        double mx = sv[0], es[KTOP], ssum = 0.0;
        for (int r = 0; r < KTOP; ++r) { es[r] = exp(sv[r] - mx); ssum += es[r]; }
        for (int r = 0; r < KTOP; ++r) { wsm[r] = (float)(es[r] / ssum); seli[r] = sx[r]; }
    }
    __syncthreads();
    for (int j = tid; j < 768; j += 256) {
        float o = 0.f;
#pragma unroll
        for (int r = 0; r < KTOP; ++r) o += wsm[r] * v[(size_t)seli[r] * 768 + j];
        retrc[(size_t)row * 768 + j] = o;
    }
}

// ---------------------------------------------------------------------------
extern "C" void kernel_launch(void* const* d_in, const int* in_sizes, int n_in,
                              void* d_out, int out_size, void* d_ws, size_t ws_size,
                              hipStream_t stream)
{
    const float* x  = (const float*)d_in[0];
    const float* Wq = (const float*)d_in[1];
    const float* bq = (const float*)d_in[2];
    const float* Wk = (const float*)d_in[3];
    const float* bk = (const float*)d_in[4];
    const float* Wv = (const float*)d_in[5];
    const float* bv = (const float*)d_in[6];
    const float* Wp = (const float*)d_in[7];
    const float* bp = (const float*)d_in[8];
    const float* pm = (const float*)d_in[9];
    float* out = (float*)d_out;
    float* ws  = (float*)d_ws;

    const float inv_sqrt_d = (float)(1.0 / sqrt((double)DD));
    const size_t TD  = (size_t)TT * DD;
    const size_t SD2 = (size_t)S2 * DD;
    const size_t WSZ = (size_t)DD * DD;

    float* p = ws;
    float* WqT = p; p += WSZ;
    float* WkT = p; p += WSZ;
    float* WvT = p; p += WSZ;
    float* WpT = p; p += WSZ;
    float* slots = p; p += SD2;
    float* q32 = p; p += TD;
    float* k32 = p; p += SD2;
    float* v32 = p; p += SD2;
    float* retr = p; p += TD;
    double* q64buf = (double*)p; p += (size_t)AMB_CAP * DD * 2;
    double* ubuf   = (double*)p; p += (size_t)AMB_CAP * DD * 2;
    double* bkqbuf = (double*)p; p += AMB_CAP * 2;
    int* cand = (int*)p; p += (size_t)AMB_CAP * 16;
    int* ambc = (int*)p; p += 64;
    int* ambrows = (int*)p; p += AMB_CAP;
    float* scores = p;
    size_t used = (size_t)(p - ws);

    long tc = TT;
    while (tc > 512 && (used + (size_t)tc * S2) * 4 > ws_size) tc >>= 1;

    transpose768<<<dim3(24, 24), 256, 0, stream>>>(Wq, WqT);
    transpose768<<<dim3(24, 24), 256, 0, stream>>>(Wk, WkT);
    transpose768<<<dim3(24, 24), 256, 0, stream>>>(Wv, WvT);
    transpose768<<<dim3(24, 24), 256, 0, stream>>>(Wp, WpT);

    for (int b = 0; b < BB; ++b) {
        const float* xb = x + (size_t)b * TD;
        build_slots<<<(SS * DD) / 256, 256, 0, stream>>>(xb, pm, slots);
        mfma_nt_split<<<dim3(6, 32), 256, 0, stream>>>(
            xb, WqT, bq, q32, DD, 1.f, 1.f);
        mfma_nt_split<<<dim3(6, 16), 256, 0, stream>>>(
            slots, WkT, bk, k32, DD, 1.f, 1.f);
        mfma_nt_f16<<<dim3(6, 16), 256, 0, stream>>>(
            slots, WvT, bv, v32, DD, 1.f, 1.f);

        for (long t0 = 0; t0 < TT; t0 += tc) {
            zero1<<<1, 1, 0, stream>>>(ambc);
            mfma_nt_split<<<dim3(16, tc / 128), 256, 0, stream>>>(
                q32 + (size_t)t0 * DD, k32, (const float*)nullptr, scores,
                S2, inv_sqrt_d, 0.f);
            select_combine<<<tc / 4, 256, 0, stream>>>(
                scores, v32, retr + (size_t)t0 * DD, ambc, ambrows, cand);
            fixup_q<<<dim3(12, AMB_CAP), 256, 0, stream>>>(
                ambc, ambrows, xb + (size_t)t0 * DD, Wq, bq, q64buf);
            fixup_u<<<dim3(12, AMB_CAP), 256, 0, stream>>>(
                ambc, WkT, bk, q64buf, ubuf, bkqbuf);
            fixup_sel<<<AMB_CAP, 256, 0, stream>>>(
                ambc, ambrows, xb, pm, cand, ubuf, bkqbuf, v32,
                retr + (size_t)t0 * DD);
        }

        mfma_nt_f16<<<dim3(6, 32), 256, 0, stream>>>(
            retr, WpT, bp, out + (size_t)b * TD, DD, RWEIGHT, RWEIGHT);
    }
}